// Round 3
// baseline (482.329 us; speedup 1.0000x reference)
//
#include <hip/hip_runtime.h>
#include <math.h>

#define H 1024
#define V 50257
#define L 512
#define NB 256     // front-end mega-kernel blocks (1 per CU; co-resident during replay)
#define RBLK 64    // reduction blocks for log-softmax

__device__ __forceinline__ float wave_sum(float v) {
#pragma unroll
    for (int off = 32; off; off >>= 1) v += __shfl_xor(v, off, 64);
    return v;
}
__device__ __forceinline__ float wave_max(float v) {
#pragma unroll
    for (int off = 32; off; off >>= 1) v = fmaxf(v, __shfl_xor(v, off, 64));
    return v;
}
__device__ __forceinline__ float sigmoidf(float x) { return 1.f / (1.f + expf(-x)); }

// Device-scope grid barrier, generation-counted (counter monotonically rises to gen*NB).
// Safe under graph replay: our kernels are alone on the device, 256 blocks of 256
// threads = 1 block/CU, all resident.
__device__ __forceinline__ void gbar(int* cnt, int gen) {
    __syncthreads();
    if (threadIdx.x == 0) {
        __threadfence();            // release: my block's writes visible device-wide
        atomicAdd(cnt, 1);
        while (__hip_atomic_load(cnt, __ATOMIC_ACQUIRE, __HIP_MEMORY_SCOPE_AGENT) < gen * NB) {
            __builtin_amdgcn_s_sleep(1);
        }
        __threadfence();            // acquire: discard stale cached lines
    }
    __syncthreads();
}

// ---- Fused front-end: attn logits -> softmax -> context -> combine+relu -> gates+LSTM
__global__ void __launch_bounds__(256) k_frontend(
        const int* __restrict__ inp, const float* __restrict__ h0,
        const float* __restrict__ c0, const float* __restrict__ emb_table,
        const float* __restrict__ W_attn, const float* __restrict__ b_attn,
        const float* __restrict__ enc,
        const float* __restrict__ W_comb, const float* __restrict__ b_comb,
        const float* __restrict__ W_ih, const float* __restrict__ W_hh,
        const float* __restrict__ b_ih, const float* __restrict__ b_hh,
        float* __restrict__ ws_logits, float* __restrict__ ws_aa,
        float* __restrict__ ws_x, int* __restrict__ cnt,
        float* __restrict__ out_attn, float* __restrict__ out_h1,
        float* __restrict__ out_c1) {
    const int t = threadIdx.x, lane = t & 63, wid = t >> 6;
    const int gw = blockIdx.x * 4 + wid;           // global wave id, 0..1023
    const float* emb = emb_table + (size_t)inp[0] * H;
    __shared__ float sh[4];
    __shared__ float g4[4][4];

    // Phase A: attn_logits[gw] for gw<512; waves 512..527 zero ws_aa
    if (gw < L) {
        const float* wrow = W_attn + (size_t)gw * (2 * H);
        float acc = 0.f;
#pragma unroll
        for (int it = 0; it < 8; ++it) {
            int k = it * 256 + lane * 4;
            float4 wv = *(const float4*)(wrow + k);
            const float* src = (k < H) ? (emb + k) : (h0 + (k - H));
            float4 xv = *(const float4*)src;
            acc += wv.x * xv.x + wv.y * xv.y + wv.z * xv.z + wv.w * xv.w;
        }
        acc = wave_sum(acc);
        if (lane == 0) ws_logits[gw] = acc + b_attn[gw];
    } else if (gw < L + 16) {
        ws_aa[(gw - L) * 64 + lane] = 0.f;
    }
    gbar(cnt, 1);

    // Phase B: redundant softmax in blocks 0..64; blocks 0..63 accumulate context,
    // block 64 writes attn weights output.
    if (blockIdx.x <= 64) {
        float v0 = ws_logits[t], v1 = ws_logits[t + 256];
        float m = wave_max(fmaxf(v0, v1));
        if (lane == 0) sh[wid] = m;
        __syncthreads();
        m = fmaxf(fmaxf(sh[0], sh[1]), fmaxf(sh[2], sh[3]));
        float e0 = expf(v0 - m), e1 = expf(v1 - m);
        float s = wave_sum(e0 + e1);
        __syncthreads();
        if (lane == 0) sh[wid] = s;
        __syncthreads();
        s = sh[0] + sh[1] + sh[2] + sh[3];
        if (blockIdx.x == 64) {
            out_attn[t] = e0 / s;
            out_attn[t + 256] = e1 / s;
        } else {
            int b = blockIdx.x;
            float4 acc = make_float4(0.f, 0.f, 0.f, 0.f);
#pragma unroll
            for (int r = 0; r < 8; ++r) {
                int l = b * 8 + r;
                float w = expf(ws_logits[l] - m) / s;
                float4 e = *(const float4*)(enc + (size_t)l * H + t * 4);
                acc.x += w * e.x; acc.y += w * e.y; acc.z += w * e.z; acc.w += w * e.w;
            }
            atomicAdd(&ws_aa[t * 4 + 0], acc.x);
            atomicAdd(&ws_aa[t * 4 + 1], acc.y);
            atomicAdd(&ws_aa[t * 4 + 2], acc.z);
            atomicAdd(&ws_aa[t * 4 + 3], acc.w);
        }
    }
    gbar(cnt, 2);

    // Phase C: x[gw] = relu(dot(cat(emb, aa), W_comb[gw]) + b_comb[gw]), gw in [0,1024)
    {
        const float* wrow = W_comb + (size_t)gw * (2 * H);
        float acc = 0.f;
#pragma unroll
        for (int it = 0; it < 8; ++it) {
            int k = it * 256 + lane * 4;
            float4 wv = *(const float4*)(wrow + k);
            const float* src = (k < H) ? (emb + k) : (ws_aa + (k - H));
            float4 xv = *(const float4*)src;
            acc += wv.x * xv.x + wv.y * xv.y + wv.z * xv.z + wv.w * xv.w;
        }
        acc = wave_sum(acc);
        if (lane == 0) ws_x[gw] = fmaxf(acc + b_comb[gw], 0.f);
    }
    gbar(cnt, 3);

    // Phase D: block b -> hidden j in [4b,4b+4); wave wid computes gate `wid` rows
    {
        int jbase = blockIdx.x * 4;
#pragma unroll
        for (int i = 0; i < 4; ++i) {
            int row = wid * H + jbase + i;
            const float* wi = W_ih + (size_t)row * H;
            const float* wh = W_hh + (size_t)row * H;
            float acc = 0.f;
#pragma unroll
            for (int it = 0; it < 4; ++it) {
                int k = it * 256 + lane * 4;
                float4 a = *(const float4*)(wi + k);
                float4 xv = *(const float4*)(ws_x + k);
                acc += a.x * xv.x + a.y * xv.y + a.z * xv.z + a.w * xv.w;
                float4 bb = *(const float4*)(wh + k);
                float4 hv = *(const float4*)(h0 + k);
                acc += bb.x * hv.x + bb.y * hv.y + bb.z * hv.z + bb.w * hv.w;
            }
            acc = wave_sum(acc);
            if (lane == 0) g4[wid][i] = acc + b_ih[row] + b_hh[row];
        }
        __syncthreads();
        if (t < 4) {
            int j = jbase + t;
            float ig = sigmoidf(g4[0][t]);
            float fg = sigmoidf(g4[1][t]);
            float gg = tanhf(g4[2][t]);
            float og = sigmoidf(g4[3][t]);
            float c1 = fg * c0[j] + ig * gg;
            out_c1[j] = c1;
            out_h1[j] = og * tanhf(c1);
        }
    }
}

// ---- k_out: logits[v] = dot(h1, W_out[v]) + b_out[v]  (the 206 MB matvec)
__global__ void k_out(const float* __restrict__ h1, const float* __restrict__ W_out,
                      const float* __restrict__ b_out, float* __restrict__ logp) {
    int wave = (blockIdx.x * blockDim.x + threadIdx.x) >> 6;
    int lane = threadIdx.x & 63;
    if (wave >= V) return;
    const float* wrow = W_out + (size_t)wave * H;
    float acc = 0.f;
#pragma unroll
    for (int it = 0; it < 4; ++it) {
        int k = it * 256 + lane * 4;
        float4 wv = *(const float4*)(wrow + k);
        float4 hv = *(const float4*)(h1 + k);
        acc += wv.x * hv.x + wv.y * hv.y + wv.z * hv.z + wv.w * hv.w;
    }
    acc = wave_sum(acc);
    if (lane == 0) logp[wave] = acc + b_out[wave];
}

// ---- k_red: per-block (max, sumexp) partials over V
__global__ void k_red(const float* __restrict__ logp, float* __restrict__ pair) {
    __shared__ float sh[4];
    int t = threadIdx.x, lane = t & 63, wid = t >> 6;
    float vals[4];
    int n = 0;
    float m = -1e30f;
    for (int v = blockIdx.x * 256 + t; v < V; v += RBLK * 256) {
        vals[n] = logp[v];
        m = fmaxf(m, vals[n]);
        ++n;
    }
    m = wave_max(m);
    if (lane == 0) sh[wid] = m;
    __syncthreads();
    float m4 = fmaxf(fmaxf(sh[0], sh[1]), fmaxf(sh[2], sh[3]));
    float s = 0.f;
    for (int i = 0; i < n; ++i) s += expf(vals[i] - m4);
    s = wave_sum(s);
    __syncthreads();
    if (lane == 0) sh[wid] = s;
    __syncthreads();
    if (t == 0) {
        pair[blockIdx.x * 2]     = m4;
        pair[blockIdx.x * 2 + 1] = sh[0] + sh[1] + sh[2] + sh[3];
    }
}

// ---- k_sub: redundant 64-pair combine + grid-wide subtract
__global__ void k_sub(float* __restrict__ logp, const float* __restrict__ pair) {
    float mg = -1e30f;
#pragma unroll
    for (int i = 0; i < RBLK; ++i) mg = fmaxf(mg, pair[2 * i]);
    float sg = 0.f;
#pragma unroll
    for (int i = 0; i < RBLK; ++i) sg += pair[2 * i + 1] * expf(pair[2 * i] - mg);
    float lse = mg + logf(sg);
    int v = blockIdx.x * blockDim.x + threadIdx.x;
    if (v < V) logp[v] -= lse;
}

extern "C" void kernel_launch(void* const* d_in, const int* in_sizes, int n_in,
                              void* d_out, int out_size, void* d_ws, size_t ws_size,
                              hipStream_t stream) {
    const int*   inp     = (const int*)d_in[0];
    const float* h0      = (const float*)d_in[1];
    const float* c0      = (const float*)d_in[2];
    const float* enc     = (const float*)d_in[3];
    const float* emb     = (const float*)d_in[4];
    const float* W_attn  = (const float*)d_in[5];
    const float* b_attn  = (const float*)d_in[6];
    const float* W_comb  = (const float*)d_in[7];
    const float* b_comb  = (const float*)d_in[8];
    const float* W_ih    = (const float*)d_in[9];
    const float* W_hh    = (const float*)d_in[10];
    const float* b_ih    = (const float*)d_in[11];
    const float* b_hh    = (const float*)d_in[12];
    const float* W_out   = (const float*)d_in[13];
    const float* b_out   = (const float*)d_in[14];

    float* out      = (float*)d_out;
    float* out_logp = out;                  // V
    float* out_h1   = out + V;              // H
    float* out_c1   = out + V + H;          // H
    float* out_attn = out + V + 2 * H;      // L

    float* ws        = (float*)d_ws;
    int*   ws_cnt    = (int*)d_ws;          // barrier counter (first 256 B zeroed)
    float* ws_logits = ws + 64;             // L
    float* ws_aa     = ws + 64 + 512;       // H
    float* ws_x      = ws + 64 + 512 + 1024;        // H
    float* ws_pair   = ws + 64 + 512 + 2048;        // 2*RBLK

    hipMemsetAsync(d_ws, 0, 256, stream);
    k_frontend<<<NB, 256, 0, stream>>>(inp, h0, c0, emb, W_attn, b_attn, enc,
                                       W_comb, b_comb, W_ih, W_hh, b_ih, b_hh,
                                       ws_logits, ws_aa, ws_x, ws_cnt,
                                       out_attn, out_h1, out_c1);
    k_out<<<(V + 3) / 4, 256, 0, stream>>>(out_h1, W_out, b_out, out_logp);
    k_red<<<RBLK, 256, 0, stream>>>(out_logp, ws_pair);
    k_sub<<<(V + 255) / 256, 256, 0, stream>>>(out_logp, ws_pair);
}